// Round 7
// baseline (17.998 us; speedup 1.0000x reference)
//
#include <hip/hip_runtime.h>

#define BB 2
#define NN 1024
#define MM 1024
#define DIN 16
#define CC 32
#define HH 32

// jax.nn.gelu approximate=True; tanh via exp + 1-ulp v_rcp (smooth path only)
__device__ __forceinline__ float gelu_tanh(float v) {
    float v3 = v * v * v;
    float u = 0.7978845608028654f * (v + 0.044715f * v3);
    float e = __expf(2.0f * u);
    float t = 1.0f - 2.0f * __builtin_amdgcn_rcpf(e + 1.0f);
    return 0.5f * v * (1.0f + t);
}

// One block per (batch b, 4 queries). 512 threads = 8 waves = 16 groups of 32.
// Groups 4q..4q+3 serve query i0+q. Wave w owns points [w*128, w*128+128).
// __launch_bounds__(512,2): cap 128 VGPR; 512 blocks all co-resident (2/CU).
__global__ __launch_bounds__(512, 2) void gno_fused(
    const float* __restrict__ pndata, const float* __restrict__ x_coord,
    const float* __restrict__ latq,
    const float* __restrict__ W_lift, const float* __restrict__ b_lift,
    const float* __restrict__ W1, const float* __restrict__ b1,
    const float* __restrict__ W2, const float* __restrict__ b2,
    float* __restrict__ out)
{
    const int bid = blockIdx.x;        // 512 blocks
    const int b = bid >> 8;
    const int i0 = (bid & 255) * 4;
    const int t = threadIdx.x;
    const int lane = t & 63;
    const int wave = t >> 6;           // 0..7
    const int g = t >> 5;              // group 0..15
    const int c = t & 31;              // channel 0..31
    const int qi = g >> 2;             // query select 0..3 (wave-uniform)
    const int sg = g & 3;              // subgroup 0..3 within query

    __shared__ float2 xs[NN];                        // rescaled coords by j
    __shared__ unsigned meta[4][NN];                 // per-query compact lists
    __shared__ __align__(16) float hbuf[2][16 * HH]; // double-buffered hidden vecs
    __shared__ float accs[16 * CC];
    __shared__ float redf[32];
    __shared__ int kcnt[4][8];
    __shared__ int k1cnt[4][8];

    // ---- per-lane weight columns (issued early; latency overlaps min/max) ----
    const float w1a = W1[c];
    const float w1b = W1[HH + c];
    const float w1c = W1[2 * HH + c];
    const float w1d = W1[3 * HH + c];
    const float b1v = b1[c];
    const float b2v = b2[c];
    const float blv = b_lift[c];
    float wl[DIN];
    #pragma unroll
    for (int k = 0; k < DIN; ++k) wl[k] = W_lift[k * CC + c];
    float w2c[HH];
    #pragma unroll
    for (int h = 0; h < HH; ++h) w2c[h] = W2[h * CC + c];

    // 4 queries' coords: i0 multiple of 4 -> 32B aligned
    const float4 qqA = *((const float4*)&latq[2 * i0]);       // q0,q1
    const float4 qqB = *((const float4*)&latq[2 * i0 + 4]);   // q2,q3

    // ---- per-block min/max; wave w owns points [w*128, w*128+128) ----
    const float2* xcb = (const float2*)x_coord + b * NN;
    float2 xyc[2];
    float mn0 = 1e30f, mx0 = -1e30f, mn1 = 1e30f, mx1 = -1e30f;
    #pragma unroll
    for (int kk = 0; kk < 2; ++kk) {
        xyc[kk] = xcb[wave * 128 + kk * 64 + lane];
        mn0 = fminf(mn0, xyc[kk].x); mx0 = fmaxf(mx0, xyc[kk].x);
        mn1 = fminf(mn1, xyc[kk].y); mx1 = fmaxf(mx1, xyc[kk].y);
    }
    #pragma unroll
    for (int off = 32; off > 0; off >>= 1) {
        mn0 = fminf(mn0, __shfl_down(mn0, off));
        mx0 = fmaxf(mx0, __shfl_down(mx0, off));
        mn1 = fminf(mn1, __shfl_down(mn1, off));
        mx1 = fmaxf(mx1, __shfl_down(mx1, off));
    }
    if (lane == 0) {
        redf[wave * 4 + 0] = mn0; redf[wave * 4 + 1] = mx0;
        redf[wave * 4 + 2] = mn1; redf[wave * 4 + 3] = mx1;
    }
    __syncthreads();                                          // barrier 1
    float Amn0 = redf[0], Amx0 = redf[1], Amn1 = redf[2], Amx1 = redf[3];
    #pragma unroll
    for (int w = 1; w < 8; ++w) {
        Amn0 = fminf(Amn0, redf[w * 4 + 0]); Amx0 = fmaxf(Amx0, redf[w * 4 + 1]);
        Amn1 = fminf(Amn1, redf[w * 4 + 2]); Amx1 = fmaxf(Amx1, redf[w * 4 + 3]);
    }
    // denom = (mx - mn) + 1e-12, each op rounded separately (matches numpy)
    const float den0 = __fadd_rn(__fsub_rn(Amx0, Amn0), 1e-12f);
    const float den1 = __fadd_rn(__fsub_rn(Amx1, Amn1), 1e-12f);

    const float t1 = 0.01f;   // (0.1*1)^2
    const float t2 = 0.04f;   // (0.1*2)^2

    // ---- Pass A phase 1: rescale -> xs, per-query hit bits + wave counts ----
    const unsigned long long lmask = (1ull << lane) - 1ull;
    unsigned bit2q[4] = {0, 0, 0, 0};
    unsigned bit1q[4] = {0, 0, 0, 0};
    int kw[4] = {0, 0, 0, 0};
    int k1w[4] = {0, 0, 0, 0};
    #pragma unroll
    for (int kk = 0; kk < 2; ++kk) {
        const int j = wave * 128 + kk * 64 + lane;
        float r0 = __fsub_rn(__fdiv_rn(__fmul_rn(2.0f, __fsub_rn(xyc[kk].x, Amn0)), den0), 1.0f);
        float r1 = __fsub_rn(__fdiv_rn(__fmul_rn(2.0f, __fsub_rn(xyc[kk].y, Amn1)), den1), 1.0f);
        xs[j] = make_float2(r0, r1);
        #pragma unroll
        for (int q = 0; q < 4; ++q) {
            const float qx = (q == 0) ? qqA.x : (q == 1) ? qqA.z : (q == 2) ? qqB.x : qqB.z;
            const float qy = (q == 0) ? qqA.y : (q == 1) ? qqA.w : (q == 2) ? qqB.y : qqB.w;
            float dx = __fsub_rn(qx, r0), dy = __fsub_rn(qy, r1);
            float d2 = __fadd_rn(__fmul_rn(dx, dx), __fmul_rn(dy, dy));
            bool h2 = d2 <= t2, h1 = d2 <= t1;
            bit2q[q] |= (h2 ? 1u : 0u) << kk;
            bit1q[q] |= (h1 ? 1u : 0u) << kk;
            kw[q] += (int)__popcll(__ballot(h2));
            k1w[q] += (int)__popcll(__ballot(h1));
        }
    }
    if (lane == 0) {
        #pragma unroll
        for (int q = 0; q < 4; ++q) { kcnt[q][wave] = kw[q]; k1cnt[q][wave] = k1w[q]; }
    }
    __syncthreads();                                          // barrier 2

    // ---- Pass A phase 2: store into per-query compact lists ----
    int base[4] = {0, 0, 0, 0};
    for (int w = 0; w < wave; ++w) {
        #pragma unroll
        for (int q = 0; q < 4; ++q) base[q] += kcnt[q][w];
    }
    #pragma unroll
    for (int kk = 0; kk < 2; ++kk) {
        const int j = wave * 128 + kk * 64 + lane;
        #pragma unroll
        for (int q = 0; q < 4; ++q) {
            bool h2 = (bit2q[q] >> kk) & 1u;
            unsigned long long m2 = __ballot(h2);
            if (h2) meta[q][base[q] + (int)__popcll(m2 & lmask)] =
                        (unsigned)j | (((bit1q[q] >> kk) & 1u) << 10);
            base[q] += (int)__popcll(m2);
        }
    }
    __syncthreads();                                          // barrier 3

    // per-query normalizers (wave-uniform qi -> no divergence)
    int K = 0, c1 = 0;
    #pragma unroll
    for (int w = 0; w < 8; ++w) { K += kcnt[qi][w]; c1 += k1cnt[qi][w]; }
    const float inv1 = 1.0f / fmaxf((float)c1, 1.0f);   // exact div, lane-identical
    const float inv2 = 1.0f / fmaxf((float)K, 1.0f);
    const float qx = (qi == 0) ? qqA.x : (qi == 1) ? qqA.z : (qi == 2) ? qqB.x : qqB.z;
    const float qy = (qi == 0) ? qqA.y : (qi == 1) ? qqA.w : (qi == 2) ? qqB.y : qqB.w;
    const float ci = fmaf(qy, w1d, fmaf(qx, w1c, b1v));

    // ---- Pass B: pipelined walk; hbuf written one iter ahead (no LDS RAW stall) ----
    float acc = 0.0f;
    const int nt = (K + 3) >> 2;
    if (nt > 0) {
        bool act = sg < K;
        unsigned m = meta[qi][act ? sg : 0];
        int j = (int)(m & 1023u);
        float wgt = ((m & 1024u) ? inv1 : 0.0f) + inv2;
        {
            float2 xy = xs[j];
            hbuf[0][g * HH + c] = gelu_tanh(fmaf(xy.y, w1b, fmaf(xy.x, w1a, ci)));
        }
        for (int it = 0; it < nt; ++it) {
            const int p = it & 1;
            // current neighbor's pndata (group-uniform broadcast loads, L2-hot)
            const float4* pd4 = (const float4*)&pndata[(b * NN + j) * DIN];
            float4 pA = pd4[0], pB4 = pd4[1], pC = pd4[2], pD = pd4[3];

            // read current hidden vector (written one full iteration ago)
            const float4* hb4 = (const float4*)&hbuf[p][g * HH];
            float4 h0 = hb4[0], h1v = hb4[1], h2v = hb4[2], h3v = hb4[3];
            float4 h4 = hb4[4], h5v = hb4[5], h6v = hb4[6], h7v = hb4[7];

            // prepare NEXT neighbor: meta, h -> hbuf[1-p] (independent work)
            bool actn = false; unsigned mn = 0; int jn = 0; float wgtn = 0.0f;
            if (it + 1 < nt) {
                const int ibn = (it + 1) * 4 + sg;
                actn = ibn < K;
                mn = meta[qi][actn ? ibn : 0];
                jn = (int)(mn & 1023u);
                wgtn = ((mn & 1024u) ? inv1 : 0.0f) + inv2;
                float2 xyn = xs[jn];
                hbuf[1 - p][g * HH + c] = gelu_tanh(fmaf(xyn.y, w1b, fmaf(xyn.x, w1a, ci)));
            }

            // kc = h . W2[:,c] (4 partial chains)
            float p0 = b2v, p1 = 0.0f, p2 = 0.0f, p3 = 0.0f;
            p0 = fmaf(h0.x,  w2c[0],  p0); p0 = fmaf(h0.y,  w2c[1],  p0);
            p0 = fmaf(h0.z,  w2c[2],  p0); p0 = fmaf(h0.w,  w2c[3],  p0);
            p1 = fmaf(h1v.x, w2c[4],  p1); p1 = fmaf(h1v.y, w2c[5],  p1);
            p1 = fmaf(h1v.z, w2c[6],  p1); p1 = fmaf(h1v.w, w2c[7],  p1);
            p2 = fmaf(h2v.x, w2c[8],  p2); p2 = fmaf(h2v.y, w2c[9],  p2);
            p2 = fmaf(h2v.z, w2c[10], p2); p2 = fmaf(h2v.w, w2c[11], p2);
            p3 = fmaf(h3v.x, w2c[12], p3); p3 = fmaf(h3v.y, w2c[13], p3);
            p3 = fmaf(h3v.z, w2c[14], p3); p3 = fmaf(h3v.w, w2c[15], p3);
            p0 = fmaf(h4.x,  w2c[16], p0); p0 = fmaf(h4.y,  w2c[17], p0);
            p0 = fmaf(h4.z,  w2c[18], p0); p0 = fmaf(h4.w,  w2c[19], p0);
            p1 = fmaf(h5v.x, w2c[20], p1); p1 = fmaf(h5v.y, w2c[21], p1);
            p1 = fmaf(h5v.z, w2c[22], p1); p1 = fmaf(h5v.w, w2c[23], p1);
            p2 = fmaf(h6v.x, w2c[24], p2); p2 = fmaf(h6v.y, w2c[25], p2);
            p2 = fmaf(h6v.z, w2c[26], p2); p2 = fmaf(h6v.w, w2c[27], p2);
            p3 = fmaf(h7v.x, w2c[28], p3); p3 = fmaf(h7v.y, w2c[29], p3);
            p3 = fmaf(h7v.z, w2c[30], p3); p3 = fmaf(h7v.w, w2c[31], p3);
            float kc = (p0 + p1) + (p2 + p3);

            // lifting f[j][c], 2 partial chains
            float f0 = blv, f1 = 0.0f;
            f0 = fmaf(pA.x, wl[0],  f0); f1 = fmaf(pA.y, wl[1],  f1);
            f0 = fmaf(pA.z, wl[2],  f0); f1 = fmaf(pA.w, wl[3],  f1);
            f0 = fmaf(pB4.x, wl[4], f0); f1 = fmaf(pB4.y, wl[5], f1);
            f0 = fmaf(pB4.z, wl[6], f0); f1 = fmaf(pB4.w, wl[7], f1);
            f0 = fmaf(pC.x, wl[8],  f0); f1 = fmaf(pC.y, wl[9],  f1);
            f0 = fmaf(pC.z, wl[10], f0); f1 = fmaf(pC.w, wl[11], f1);
            f0 = fmaf(pD.x, wl[12], f0); f1 = fmaf(pD.y, wl[13], f1);
            f0 = fmaf(pD.z, wl[14], f0); f1 = fmaf(pD.w, wl[15], f1);
            float fv = f0 + f1;

            if (act) acc = fmaf(wgt, kc * fv, acc);

            act = actn; m = mn; j = jn; wgt = wgtn;   // rotate carried state
        }
    }
    accs[g * CC + c] = acc;
    __syncthreads();                                          // barrier 4
    if (t < 128) {
        const int q2 = t >> 5;       // output query 0..3
        const int cc = t & 31;
        float s = (accs[(q2 * 4 + 0) * CC + cc] + accs[(q2 * 4 + 1) * CC + cc]) +
                  (accs[(q2 * 4 + 2) * CC + cc] + accs[(q2 * 4 + 3) * CC + cc]);
        out[(b * MM + i0 + q2) * CC + cc] = s;
    }
}

extern "C" void kernel_launch(void* const* d_in, const int* in_sizes, int n_in,
                              void* d_out, int out_size, void* d_ws, size_t ws_size,
                              hipStream_t stream) {
    const float* pndata = (const float*)d_in[0];   // [B,N,16]
    const float* x_coord = (const float*)d_in[1];  // [B,N,2]
    const float* latq = (const float*)d_in[2];     // [M,2]
    const float* W_lift = (const float*)d_in[3];   // [16,32]
    const float* b_lift = (const float*)d_in[4];   // [32]
    const float* W1 = (const float*)d_in[5];       // [4,32]
    const float* b1 = (const float*)d_in[6];       // [32]
    const float* W2 = (const float*)d_in[7];       // [32,32]
    const float* b2 = (const float*)d_in[8];       // [32]
    float* out = (float*)d_out;                    // [B,M,32]

    gno_fused<<<BB * MM / 4, 512, 0, stream>>>(pndata, x_coord, latq,
                                               W_lift, b_lift, W1, b1, W2, b2, out);
}

// Round 8
// 17.572 us; speedup vs baseline: 1.0242x; 1.0242x over previous
//
#include <hip/hip_runtime.h>

#define BB 2
#define NN 1024
#define MM 1024
#define DIN 16
#define CC 32
#define HH 32

// jax.nn.gelu approximate=True; tanh via exp + 1-ulp v_rcp (smooth path only)
__device__ __forceinline__ float gelu_tanh(float v) {
    float v3 = v * v * v;
    float u = 0.7978845608028654f * (v + 0.044715f * v3);
    float e = __expf(2.0f * u);
    float t = 1.0f - 2.0f * __builtin_amdgcn_rcpf(e + 1.0f);
    return 0.5f * v * (1.0f + t);
}

// One block per (batch b, query-pair). 256 threads = 4 waves; 8 groups of 32.
// wave0,1 -> query i0 (groups 0-3); wave2,3 -> query i0+1 (groups 4-7).
// __launch_bounds__(256,4): cap VGPR at 128 so all 1024 blocks are co-resident
// in ONE residency round (4096 waves = 16 waves/CU across 256 CUs).
__global__ __launch_bounds__(256, 4) void gno_fused(
    const float* __restrict__ pndata, const float* __restrict__ x_coord,
    const float* __restrict__ latq,
    const float* __restrict__ W_lift, const float* __restrict__ b_lift,
    const float* __restrict__ W1, const float* __restrict__ b1,
    const float* __restrict__ W2, const float* __restrict__ b2,
    float* __restrict__ out)
{
    const int bid = blockIdx.x;        // 1024 blocks
    const int b = bid >> 9;
    const int i0 = (bid & 511) * 2;
    const int t = threadIdx.x;
    const int lane = t & 63;
    const int wave = t >> 6;
    const int g = t >> 5;              // group 0..7
    const int c = t & 31;              // channel 0..31
    const int qi = g >> 2;             // query select (wave-uniform!)
    const int sg = g & 3;              // subgroup 0..3 within query

    __shared__ float2 xs[NN];                       // rescaled coords by j
    __shared__ unsigned meta[2][NN];                // per-query single compact list
    __shared__ __align__(16) float hbuf[2][8 * HH]; // double-buffered hidden vecs
    __shared__ float accs[8 * CC];
    __shared__ float redf[16];
    __shared__ int kcnt[2][4];
    __shared__ int k1cnt[2][4];

    // ---- per-lane weight columns ----
    const float w1a = W1[c];
    const float w1b = W1[HH + c];
    const float w1c = W1[2 * HH + c];
    const float w1d = W1[3 * HH + c];
    const float b1v = b1[c];
    const float b2v = b2[c];
    const float blv = b_lift[c];
    float wl[DIN];
    #pragma unroll
    for (int k = 0; k < DIN; ++k) wl[k] = W_lift[k * CC + c];
    float w2c[HH];
    #pragma unroll
    for (int h = 0; h < HH; ++h) w2c[h] = W2[h * CC + c];

    const float4 qq = *((const float4*)&latq[2 * i0]);   // (q0x,q0y,q1x,q1y)

    // ---- per-block min/max; wave w owns points [wave*256, wave*256+256) ----
    const float2* xcb = (const float2*)x_coord + b * NN;
    float2 xyc[4];
    float mn0 = 1e30f, mx0 = -1e30f, mn1 = 1e30f, mx1 = -1e30f;
    #pragma unroll
    for (int kk = 0; kk < 4; ++kk) {
        xyc[kk] = xcb[wave * 256 + kk * 64 + lane];
        mn0 = fminf(mn0, xyc[kk].x); mx0 = fmaxf(mx0, xyc[kk].x);
        mn1 = fminf(mn1, xyc[kk].y); mx1 = fmaxf(mx1, xyc[kk].y);
    }
    #pragma unroll
    for (int off = 32; off > 0; off >>= 1) {
        mn0 = fminf(mn0, __shfl_down(mn0, off));
        mx0 = fmaxf(mx0, __shfl_down(mx0, off));
        mn1 = fminf(mn1, __shfl_down(mn1, off));
        mx1 = fmaxf(mx1, __shfl_down(mx1, off));
    }
    if (lane == 0) {
        redf[wave * 4 + 0] = mn0; redf[wave * 4 + 1] = mx0;
        redf[wave * 4 + 2] = mn1; redf[wave * 4 + 3] = mx1;
    }
    __syncthreads();                                          // barrier 1
    const float Amn0 = fminf(fminf(redf[0], redf[4]),  fminf(redf[8],  redf[12]));
    const float Amx0 = fmaxf(fmaxf(redf[1], redf[5]),  fmaxf(redf[9],  redf[13]));
    const float Amn1 = fminf(fminf(redf[2], redf[6]),  fminf(redf[10], redf[14]));
    const float Amx1 = fmaxf(fmaxf(redf[3], redf[7]),  fmaxf(redf[11], redf[15]));
    const float den0 = __fadd_rn(__fsub_rn(Amx0, Amn0), 1e-12f);
    const float den1 = __fadd_rn(__fsub_rn(Amx1, Amn1), 1e-12f);

    const float t1 = 0.01f;   // (0.1*1)^2
    const float t2 = 0.04f;   // (0.1*2)^2

    // ---- Pass A phase 1: rescale -> xs, d2 hit-bits (kept in regs), wave counts ----
    const unsigned long long lmask = (1ull << lane) - 1ull;
    unsigned bit20 = 0, bit10 = 0, bit21 = 0, bit11 = 0;
    int kw0 = 0, k1w0 = 0, kw1 = 0, k1w1 = 0;
    #pragma unroll
    for (int kk = 0; kk < 4; ++kk) {
        const int j = wave * 256 + kk * 64 + lane;
        float r0 = __fsub_rn(__fdiv_rn(__fmul_rn(2.0f, __fsub_rn(xyc[kk].x, Amn0)), den0), 1.0f);
        float r1 = __fsub_rn(__fdiv_rn(__fmul_rn(2.0f, __fsub_rn(xyc[kk].y, Amn1)), den1), 1.0f);
        xs[j] = make_float2(r0, r1);
        {
            float dx = __fsub_rn(qq.x, r0), dy = __fsub_rn(qq.y, r1);
            float d2 = __fadd_rn(__fmul_rn(dx, dx), __fmul_rn(dy, dy));
            bool h2 = d2 <= t2, h1 = d2 <= t1;
            bit20 |= (h2 ? 1u : 0u) << kk;  bit10 |= (h1 ? 1u : 0u) << kk;
            kw0 += (int)__popcll(__ballot(h2));
            k1w0 += (int)__popcll(__ballot(h1));
        }
        {
            float dx = __fsub_rn(qq.z, r0), dy = __fsub_rn(qq.w, r1);
            float d2 = __fadd_rn(__fmul_rn(dx, dx), __fmul_rn(dy, dy));
            bool h2 = d2 <= t2, h1 = d2 <= t1;
            bit21 |= (h2 ? 1u : 0u) << kk;  bit11 |= (h1 ? 1u : 0u) << kk;
            kw1 += (int)__popcll(__ballot(h2));
            k1w1 += (int)__popcll(__ballot(h1));
        }
    }
    if (lane == 0) {
        kcnt[0][wave] = kw0; k1cnt[0][wave] = k1w0;
        kcnt[1][wave] = kw1; k1cnt[1][wave] = k1w1;
    }
    __syncthreads();                                          // barrier 2

    // ---- Pass A phase 2: store into single per-query compact list ----
    int base0 = 0, base1 = 0;
    if (wave > 0) { base0 += kcnt[0][0]; base1 += kcnt[1][0]; }
    if (wave > 1) { base0 += kcnt[0][1]; base1 += kcnt[1][1]; }
    if (wave > 2) { base0 += kcnt[0][2]; base1 += kcnt[1][2]; }
    #pragma unroll
    for (int kk = 0; kk < 4; ++kk) {
        const int j = wave * 256 + kk * 64 + lane;
        {
            bool h2 = (bit20 >> kk) & 1u;
            unsigned long long m2 = __ballot(h2);
            if (h2) meta[0][base0 + (int)__popcll(m2 & lmask)] =
                        (unsigned)j | (((bit10 >> kk) & 1u) << 10);
            base0 += (int)__popcll(m2);
        }
        {
            bool h2 = (bit21 >> kk) & 1u;
            unsigned long long m2 = __ballot(h2);
            if (h2) meta[1][base1 + (int)__popcll(m2 & lmask)] =
                        (unsigned)j | (((bit11 >> kk) & 1u) << 10);
            base1 += (int)__popcll(m2);
        }
    }
    __syncthreads();                                          // barrier 3

    const int K  = kcnt[qi][0] + kcnt[qi][1] + kcnt[qi][2] + kcnt[qi][3];
    const int c1 = k1cnt[qi][0] + k1cnt[qi][1] + k1cnt[qi][2] + k1cnt[qi][3];
    const float inv1 = 1.0f / fmaxf((float)c1, 1.0f);   // exact, lane-identical
    const float inv2 = 1.0f / fmaxf((float)K, 1.0f);
    const float qx = qi ? qq.z : qq.x;
    const float qy = qi ? qq.w : qq.y;
    const float ci = fmaf(qy, w1d, fmaf(qx, w1c, b1v));

    // ---- Pass B: pipelined walk; hbuf written one iter ahead (no LDS RAW stall) ----
    float acc = 0.0f;
    const int nt = (K + 3) >> 2;
    if (nt > 0) {
        // prologue: neighbor (it=0) h -> hbuf[0]; carry its meta in regs
        bool act = sg < K;
        unsigned m = meta[qi][act ? sg : 0];
        int j = (int)(m & 1023u);
        float wgt = ((m & 1024u) ? inv1 : 0.0f) + inv2;
        {
            float2 xy = xs[j];
            float hv = gelu_tanh(fmaf(xy.y, w1b, fmaf(xy.x, w1a, ci)));
            hbuf[0][g * HH + c] = hv;
        }
        for (int it = 0; it < nt; ++it) {
            const int p = it & 1;
            // current neighbor's pndata (group-uniform broadcast loads, L2-hot)
            const float4* pd4 = (const float4*)&pndata[(b * NN + j) * DIN];
            float4 pA = pd4[0], pB4 = pd4[1], pC = pd4[2], pD = pd4[3];

            // read current hidden vector (written one full iteration ago)
            const float4* hb4 = (const float4*)&hbuf[p][g * HH];
            float4 h0 = hb4[0], h1v = hb4[1], h2v = hb4[2], h3v = hb4[3];
            float4 h4 = hb4[4], h5v = hb4[5], h6v = hb4[6], h7v = hb4[7];

            // prepare NEXT neighbor: meta, h -> hbuf[1-p] (independent work)
            bool actn = false; unsigned mn = 0; int jn = 0; float wgtn = 0.0f;
            if (it + 1 < nt) {
                const int ibn = (it + 1) * 4 + sg;
                actn = ibn < K;
                mn = meta[qi][actn ? ibn : 0];
                jn = (int)(mn & 1023u);
                wgtn = ((mn & 1024u) ? inv1 : 0.0f) + inv2;
                float2 xyn = xs[jn];
                float hn = gelu_tanh(fmaf(xyn.y, w1b, fmaf(xyn.x, w1a, ci)));
                hbuf[1 - p][g * HH + c] = hn;
            }

            // kc = h . W2[:,c] (4 partial chains)
            float p0 = b2v, p1 = 0.0f, p2 = 0.0f, p3 = 0.0f;
            p0 = fmaf(h0.x,  w2c[0],  p0); p0 = fmaf(h0.y,  w2c[1],  p0);
            p0 = fmaf(h0.z,  w2c[2],  p0); p0 = fmaf(h0.w,  w2c[3],  p0);
            p1 = fmaf(h1v.x, w2c[4],  p1); p1 = fmaf(h1v.y, w2c[5],  p1);
            p1 = fmaf(h1v.z, w2c[6],  p1); p1 = fmaf(h1v.w, w2c[7],  p1);
            p2 = fmaf(h2v.x, w2c[8],  p2); p2 = fmaf(h2v.y, w2c[9],  p2);
            p2 = fmaf(h2v.z, w2c[10], p2); p2 = fmaf(h2v.w, w2c[11], p2);
            p3 = fmaf(h3v.x, w2c[12], p3); p3 = fmaf(h3v.y, w2c[13], p3);
            p3 = fmaf(h3v.z, w2c[14], p3); p3 = fmaf(h3v.w, w2c[15], p3);
            p0 = fmaf(h4.x,  w2c[16], p0); p0 = fmaf(h4.y,  w2c[17], p0);
            p0 = fmaf(h4.z,  w2c[18], p0); p0 = fmaf(h4.w,  w2c[19], p0);
            p1 = fmaf(h5v.x, w2c[20], p1); p1 = fmaf(h5v.y, w2c[21], p1);
            p1 = fmaf(h5v.z, w2c[22], p1); p1 = fmaf(h5v.w, w2c[23], p1);
            p2 = fmaf(h6v.x, w2c[24], p2); p2 = fmaf(h6v.y, w2c[25], p2);
            p2 = fmaf(h6v.z, w2c[26], p2); p2 = fmaf(h6v.w, w2c[27], p2);
            p3 = fmaf(h7v.x, w2c[28], p3); p3 = fmaf(h7v.y, w2c[29], p3);
            p3 = fmaf(h7v.z, w2c[30], p3); p3 = fmaf(h7v.w, w2c[31], p3);
            float kc = (p0 + p1) + (p2 + p3);

            // lifting f[j][c], 2 partial chains
            float f0 = blv, f1 = 0.0f;
            f0 = fmaf(pA.x, wl[0],  f0); f1 = fmaf(pA.y, wl[1],  f1);
            f0 = fmaf(pA.z, wl[2],  f0); f1 = fmaf(pA.w, wl[3],  f1);
            f0 = fmaf(pB4.x, wl[4], f0); f1 = fmaf(pB4.y, wl[5], f1);
            f0 = fmaf(pB4.z, wl[6], f0); f1 = fmaf(pB4.w, wl[7], f1);
            f0 = fmaf(pC.x, wl[8],  f0); f1 = fmaf(pC.y, wl[9],  f1);
            f0 = fmaf(pC.z, wl[10], f0); f1 = fmaf(pC.w, wl[11], f1);
            f0 = fmaf(pD.x, wl[12], f0); f1 = fmaf(pD.y, wl[13], f1);
            f0 = fmaf(pD.z, wl[14], f0); f1 = fmaf(pD.w, wl[15], f1);
            float fv = f0 + f1;

            if (act) acc = fmaf(wgt, kc * fv, acc);

            act = actn; m = mn; j = jn; wgt = wgtn;   // rotate carried state
        }
    }
    accs[g * CC + c] = acc;
    __syncthreads();                                          // barrier 4
    if (t < 64) {
        const int q2 = t >> 5;
        const int cc = t & 31;
        float s = (accs[(q2 * 4 + 0) * CC + cc] + accs[(q2 * 4 + 1) * CC + cc]) +
                  (accs[(q2 * 4 + 2) * CC + cc] + accs[(q2 * 4 + 3) * CC + cc]);
        out[(b * MM + i0 + q2) * CC + cc] = s;
    }
}

extern "C" void kernel_launch(void* const* d_in, const int* in_sizes, int n_in,
                              void* d_out, int out_size, void* d_ws, size_t ws_size,
                              hipStream_t stream) {
    const float* pndata = (const float*)d_in[0];   // [B,N,16]
    const float* x_coord = (const float*)d_in[1];  // [B,N,2]
    const float* latq = (const float*)d_in[2];     // [M,2]
    const float* W_lift = (const float*)d_in[3];   // [16,32]
    const float* b_lift = (const float*)d_in[4];   // [32]
    const float* W1 = (const float*)d_in[5];       // [4,32]
    const float* b1 = (const float*)d_in[6];       // [32]
    const float* W2 = (const float*)d_in[7];       // [32,32]
    const float* b2 = (const float*)d_in[8];       // [32]
    float* out = (float*)d_out;                    // [B,M,32]

    gno_fused<<<BB * MM / 2, 256, 0, stream>>>(pndata, x_coord, latq,
                                               W_lift, b_lift, W1, b1, W2, b2, out);
}